// Round 5
// baseline (39.331 us; speedup 1.0000x reference)
//
#include <hip/hip_runtime.h>

#define SEQ 128
#define SD 15
#define REC 32   // floats per (b,s) record in dba_params
#define UPF 16   // chain prefetch/unroll depth (float4 records in registers)

// ---------------------------------------------------------------------------
// Full path (ws >= 16 MB):
//   K_A prep : per-row block. Read 32 B record heads, shuffle-scan positions,
//              write compact pre-scaled dq -> qd[b*SEQ+s] and final pos ->
//              posb[b*SEQ+s] (both float4, coalesced; 16 MB total, L2/L3-hot).
//   K_B chain: one row per lane. Stream dq from the compact buffer
//              (16 B/lane/iter, cache-resident) through a 16-deep register
//              ring; overwrite consumed dq slots with the resulting quats
//              (each slot's dq is ring-resident well before q[t] is stored —
//              same thread, program order preserves the dependency).
//   K_C out  : per-row block. Read pos+quat coalesced, pack 15-float records
//              in LDS (stride 15 coprime with 32 banks), write row as 480
//              contiguous float4s — every out-line written exactly once.
// ---------------------------------------------------------------------------

__global__ __launch_bounds__(128) void prep_kernel(const float* __restrict__ dba,
                                                   const float* __restrict__ gt,
                                                   float4* __restrict__ qd,
                                                   float4* __restrict__ posb) {
    const int b = blockIdx.x;
    const int s = threadIdx.x;
    const int lane = s & 63;
    const int wave = s >> 6;

    const float* rec = dba + ((size_t)b * SEQ + s) * REC;
    const float4 h0 = *reinterpret_cast<const float4*>(rec);
    const float4 h1 = *reinterpret_cast<const float4*>(rec + 4);

    // Compact pre-scaled dq.
    qd[(size_t)b * SEQ + s] =
        make_float4(h0.w * 0.1f, h1.x * 0.1f, h1.y * 0.1f, h1.z * 0.1f);

    // Position scan.
    const float d0 = h0.x * 0.1f, d1 = h0.y * 0.1f, d2 = h0.z * 0.1f;
    float ix = d0, iy = d1, iz = d2;
#pragma unroll
    for (int off = 1; off < 64; off <<= 1) {
        const float tx = __shfl_up(ix, off, 64);
        const float ty = __shfl_up(iy, off, 64);
        const float tz = __shfl_up(iz, off, 64);
        if (lane >= off) { ix += tx; iy += ty; iz += tz; }
    }
    __shared__ float w0tot[3];
    if (wave == 0 && lane == 63) { w0tot[0] = ix; w0tot[1] = iy; w0tot[2] = iz; }
    __syncthreads();
    if (wave == 1) { ix += w0tot[0]; iy += w0tot[1]; iz += w0tot[2]; }

    const float* g = gt + (size_t)b * SEQ * SD;   // broadcast load
    posb[(size_t)b * SEQ + s] =
        make_float4(g[0] + ix - d0, g[1] + iy - d1, g[2] + iz - d2, 0.f);
}

__global__ __launch_bounds__(64) void chain_kernel(float4* __restrict__ qd,
                                                   const float* __restrict__ gt,
                                                   int B) {
    const int r = blockIdx.x * 64 + threadIdx.x;
    if (r >= B) return;
    const size_t base = (size_t)r * SEQ;

    float4 ring[UPF];
#pragma unroll
    for (int u = 0; u < UPF; ++u) ring[u] = qd[base + u];

    const float* g = gt + (size_t)r * SEQ * SD;
    float q0 = g[3], q1 = g[4], q2 = g[5], q3 = g[6];
    qd[base] = make_float4(q0, q1, q2, q3);       // slot 0 already ring-held

    for (int t0 = 0; t0 + UPF < SEQ; t0 += UPF) { // t0 = 0,16,...,96 -> t=1..112
#pragma unroll
        for (int u = 0; u < UPF; ++u) {
            const int t = t0 + u + 1;
            q0 += ring[u].x; q1 += ring[u].y; q2 += ring[u].z; q3 += ring[u].w;
            ring[u] = qd[base + t0 + UPF + u];    // refill slot (t+15), cache hit
            const float n   = q0 * q0 + q1 * q1 + q2 * q2 + q3 * q3;
            const float inv = __builtin_amdgcn_rsqf(n);
            q0 *= inv; q1 *= inv; q2 *= inv; q3 *= inv;
            qd[base + t] = make_float4(q0, q1, q2, q3);
        }
    }
#pragma unroll
    for (int u = 0; u < UPF - 1; ++u) {           // tail t = 113..127
        const int t = (SEQ - UPF) + u + 1;
        q0 += ring[u].x; q1 += ring[u].y; q2 += ring[u].z; q3 += ring[u].w;
        const float n   = q0 * q0 + q1 * q1 + q2 * q2 + q3 * q3;
        const float inv = __builtin_amdgcn_rsqf(n);
        q0 *= inv; q1 *= inv; q2 *= inv; q3 *= inv;
        qd[base + t] = make_float4(q0, q1, q2, q3);
    }
}

__global__ __launch_bounds__(128) void out_kernel(const float4* __restrict__ qd,
                                                  const float4* __restrict__ posb,
                                                  float* __restrict__ out) {
    const int b = blockIdx.x;
    const int s = threadIdx.x;
    const float4 p = posb[(size_t)b * SEQ + s];
    const float4 q = qd[(size_t)b * SEQ + s];

    __shared__ float st[SEQ * SD];
    float* rp = st + s * SD;
    rp[0] = p.x; rp[1] = p.y; rp[2] = p.z;
    rp[3] = q.x; rp[4] = q.y; rp[5] = q.z; rp[6] = q.w;
#pragma unroll
    for (int k = 7; k < SD; ++k) rp[k] = 0.f;
    __syncthreads();

    float4* o4 = reinterpret_cast<float4*>(out + (size_t)b * SEQ * SD);
    const float4* s4 = reinterpret_cast<const float4*>(st);
    // 480 float4s over 128 threads: k = s, s+128, s+256, s+384 (s<96 only
    // for the last pass) — properly bounded this time.
    for (int k = s; k < SEQ * SD / 4; k += 128)
        o4[k] = s4[k];
}

// ---------------------------------------------------------------------------
// Fallback path (R2 structure) if ws is too small for the full pipeline.
// ---------------------------------------------------------------------------
template <bool TO_WS>
__global__ __launch_bounds__(64) void quat_fb(const float* __restrict__ dba,
                                              const float* __restrict__ gt,
                                              float* __restrict__ dst, int B) {
    const int r = blockIdx.x * 64 + threadIdx.x;
    if (r >= B) return;
    const float* rec = dba + (size_t)r * SEQ * REC;
    const float* g   = gt  + (size_t)r * SEQ * SD;
    float q0 = g[3], q1 = g[4], q2 = g[5], q3 = g[6];
    float w[UPF]; float4 v[UPF];
#pragma unroll
    for (int u = 0; u < UPF; ++u) {
        const float* p = rec + (size_t)u * REC;
        w[u] = p[3]; v[u] = *reinterpret_cast<const float4*>(p + 4);
    }
    if (TO_WS) *reinterpret_cast<float4*>(dst + (size_t)r * SEQ * 4) = make_float4(q0,q1,q2,q3);
    else { float* o = dst + (size_t)r * SEQ * SD; o[3]=q0; o[4]=q1; o[5]=q2; o[6]=q3; }
    for (int t0 = 0; t0 + UPF < SEQ; t0 += UPF) {
#pragma unroll
        for (int u = 0; u < UPF; ++u) {
            const int t = t0 + u + 1;
            q0 += w[u]*0.1f; q1 += v[u].x*0.1f; q2 += v[u].y*0.1f; q3 += v[u].z*0.1f;
            const float* p = rec + (size_t)(t0 + UPF + u) * REC;
            w[u] = p[3]; v[u] = *reinterpret_cast<const float4*>(p + 4);
            const float inv = __builtin_amdgcn_rsqf(q0*q0+q1*q1+q2*q2+q3*q3);
            q0*=inv; q1*=inv; q2*=inv; q3*=inv;
            if (TO_WS) *reinterpret_cast<float4*>(dst + ((size_t)r*SEQ+t)*4) = make_float4(q0,q1,q2,q3);
            else { float* o = dst + ((size_t)r*SEQ+t)*SD; o[3]=q0; o[4]=q1; o[5]=q2; o[6]=q3; }
        }
    }
#pragma unroll
    for (int u = 0; u < UPF - 1; ++u) {
        const int t = (SEQ - UPF) + u + 1;
        q0 += w[u]*0.1f; q1 += v[u].x*0.1f; q2 += v[u].y*0.1f; q3 += v[u].z*0.1f;
        const float inv = __builtin_amdgcn_rsqf(q0*q0+q1*q1+q2*q2+q3*q3);
        q0*=inv; q1*=inv; q2*=inv; q3*=inv;
        if (TO_WS) *reinterpret_cast<float4*>(dst + ((size_t)r*SEQ+t)*4) = make_float4(q0,q1,q2,q3);
        else { float* o = dst + ((size_t)r*SEQ+t)*SD; o[3]=q0; o[4]=q1; o[5]=q2; o[6]=q3; }
    }
}

template <bool HAVE_WS>
__global__ __launch_bounds__(128) void assemble_fb(const float* __restrict__ dba,
                                                   const float* __restrict__ gt,
                                                   const float4* __restrict__ wsq,
                                                   float* __restrict__ out) {
    const int b = blockIdx.x, s = threadIdx.x, lane = s & 63, wave = s >> 6;
    const float4 h = *reinterpret_cast<const float4*>(dba + ((size_t)b*SEQ + s) * REC);
    const float d0 = h.x*0.1f, d1 = h.y*0.1f, d2 = h.z*0.1f;
    float ix = d0, iy = d1, iz = d2;
#pragma unroll
    for (int off = 1; off < 64; off <<= 1) {
        const float tx = __shfl_up(ix, off, 64);
        const float ty = __shfl_up(iy, off, 64);
        const float tz = __shfl_up(iz, off, 64);
        if (lane >= off) { ix += tx; iy += ty; iz += tz; }
    }
    __shared__ float w0tot[3];
    if (wave == 0 && lane == 63) { w0tot[0]=ix; w0tot[1]=iy; w0tot[2]=iz; }
    __syncthreads();
    if (wave == 1) { ix += w0tot[0]; iy += w0tot[1]; iz += w0tot[2]; }
    const float* g = gt + (size_t)b * SEQ * SD;
    const float px = g[0]+ix-d0, py = g[1]+iy-d1, pz = g[2]+iz-d2;
    if (HAVE_WS) {
        const float4 q = wsq[(size_t)b * SEQ + s];
        __shared__ float st[SEQ * SD];
        float* rp = st + s * SD;
        rp[0]=px; rp[1]=py; rp[2]=pz; rp[3]=q.x; rp[4]=q.y; rp[5]=q.z; rp[6]=q.w;
#pragma unroll
        for (int k = 7; k < SD; ++k) rp[k] = 0.f;
        __syncthreads();
        float4* o4 = reinterpret_cast<float4*>(out + (size_t)b * SEQ * SD);
        const float4* s4 = reinterpret_cast<const float4*>(st);
        for (int k = s; k < SEQ * SD / 4; k += 128) o4[k] = s4[k];
    } else {
        float* o = out + ((size_t)b * SEQ + s) * SD;
        o[0]=px; o[1]=py; o[2]=pz;
#pragma unroll
        for (int k = 7; k < SD; ++k) o[k] = 0.f;
    }
}

extern "C" void kernel_launch(void* const* d_in, const int* in_sizes, int n_in,
                              void* d_out, int out_size, void* d_ws, size_t ws_size,
                              hipStream_t stream) {
    const float* dba = (const float*)d_in[0];   // (B, 128, 32)
    // d_in[1] = imu_measurements — unused by the reference
    const float* gt  = (const float*)d_in[2];   // (B, 128, 15)
    float* out = (float*)d_out;                 // (B, 128, 15)

    const int B = in_sizes[0] / (SEQ * REC);
    const size_t slot = (size_t)B * SEQ;        // float4 count per buffer
    const size_t needFull = slot * 2 * sizeof(float4);   // 16 MB @ B=4096
    const size_t needMid  = slot * sizeof(float4);       //  8 MB

    if (ws_size >= needFull) {
        float4* qd   = (float4*)d_ws;
        float4* posb = qd + slot;
        prep_kernel <<<B, 128, 0, stream>>>(dba, gt, qd, posb);
        chain_kernel<<<(B + 63) / 64, 64, 0, stream>>>(qd, gt, B);
        out_kernel  <<<B, 128, 0, stream>>>(qd, posb, out);
    } else if (ws_size >= needMid) {
        float* wsq = (float*)d_ws;
        quat_fb<true>     <<<(B + 63) / 64, 64, 0, stream>>>(dba, gt, wsq, B);
        assemble_fb<true> <<<B, 128, 0, stream>>>(dba, gt, (const float4*)wsq, out);
    } else {
        quat_fb<false>     <<<(B + 63) / 64, 64, 0, stream>>>(dba, gt, out, B);
        assemble_fb<false> <<<B, 128, 0, stream>>>(dba, gt, nullptr, out);
    }
}

// Round 6
// 27.800 us; speedup vs baseline: 1.4148x; 1.4148x over previous
//
#include <hip/hip_runtime.h>

#define SEQ 128
#define SD  15
#define REC 32    // floats per (b,s) record in dba_params
#define RPB 4     // rows per block
#define NT  (RPB * SEQ)   // 512 threads, 8 waves

// ---------------------------------------------------------------------------
// Single fused kernel. Block = 4 batch rows.
//  P1: thread (row,s) loads record head (2 x float4 from one 64B line),
//      stores pre-scaled dq -> LDS, shuffle-scans positions in registers.
//  P2: lanes 0..3 of wave 0 each run one row's 127-step quaternion chain,
//      reading dq from LDS through an 8-deep register ring (256-cyc slack vs
//      ~120-cyc LDS latency) and writing quats to LDS. Meanwhile the other
//      threads write the 8 zero-columns of their output record, overlapping
//      the serial phase with ~half the store traffic.
//  P3: all threads write pos (init + exclusive prefix) and quat.
// No workspace, no inter-kernel L2 drains; all blocks co-resident
// (16.7 KB LDS, 4 blocks/CU at <=64 VGPR target).
// ---------------------------------------------------------------------------
__global__ __launch_bounds__(NT, 8) void fused_kernel(const float* __restrict__ dba,
                                                      const float* __restrict__ gt,
                                                      float* __restrict__ out,
                                                      int B) {
    const int tid  = threadIdx.x;
    const int row  = tid >> 7;          // 0..3
    const int s    = tid & (SEQ - 1);   // 0..127
    const int lane = tid & 63;
    const int half = s >> 6;            // which wave of the row's two
    const int r    = blockIdx.x * RPB + row;
    const bool valid = (r < B);

    __shared__ float4 sdq  [RPB][SEQ + 1];   // +1 pad: chain lanes stride 2064B -> distinct banks
    __shared__ float4 squat[RPB][SEQ + 1];
    __shared__ float  ginit[RPB][8];
    __shared__ float  w0tot[RPB][3];

    // ---- P1: loads + pos scan ----
    float d0 = 0.f, d1 = 0.f, d2 = 0.f;
    if (valid) {
        const float* rec = dba + ((size_t)r * SEQ + s) * REC;
        const float4 h0 = *reinterpret_cast<const float4*>(rec);
        const float4 h1 = *reinterpret_cast<const float4*>(rec + 4);
        sdq[row][s] = make_float4(h0.w * 0.1f, h1.x * 0.1f, h1.y * 0.1f, h1.z * 0.1f);
        d0 = h0.x * 0.1f; d1 = h0.y * 0.1f; d2 = h0.z * 0.1f;
        if (s == 0) {
            const float* g = gt + (size_t)r * SEQ * SD;   // 16B-aligned (7680B rows)
            *reinterpret_cast<float4*>(&ginit[row][0]) = *reinterpret_cast<const float4*>(g);
            *reinterpret_cast<float4*>(&ginit[row][4]) = *reinterpret_cast<const float4*>(g + 4);
        }
    }

    float ix = d0, iy = d1, iz = d2;       // wave-local inclusive scan
#pragma unroll
    for (int off = 1; off < 64; off <<= 1) {
        const float tx = __shfl_up(ix, off, 64);
        const float ty = __shfl_up(iy, off, 64);
        const float tz = __shfl_up(iz, off, 64);
        if (lane >= off) { ix += tx; iy += ty; iz += tz; }
    }
    if (half == 0 && lane == 63) {
        w0tot[row][0] = ix; w0tot[row][1] = iy; w0tot[row][2] = iz;
    }
    __syncthreads();
    if (half == 1) { ix += w0tot[row][0]; iy += w0tot[row][1]; iz += w0tot[row][2]; }

    // ---- P2a: overlap — zero columns written while chains run ----
    float* o = out + ((size_t)r * SEQ + s) * SD;
    if (valid) {
#pragma unroll
        for (int k = 7; k < SD; ++k) o[k] = 0.f;
    }

    // ---- P2b: quaternion chains, 4 lanes of wave 0 ----
    if (tid < RPB && blockIdx.x * RPB + tid < B) {
        const float4* srow = sdq[tid];
        float4*       qrow = squat[tid];
        float q0 = ginit[tid][3], q1 = ginit[tid][4],
              q2 = ginit[tid][5], q3 = ginit[tid][6];
        qrow[0] = make_float4(q0, q1, q2, q3);     // t=0: init_q, NOT normalized

        float4 ring[8];
#pragma unroll
        for (int u = 0; u < 8; ++u) ring[u] = srow[u];

        // 15 windows of 8 steps (t = 1..120), refilling one window ahead;
        // last refill index = 14*8+7+8 = 127 (in-bounds, value unused).
        for (int w = 0; w < 15; ++w) {
#pragma unroll
            for (int u = 0; u < 8; ++u) {
                const int t = w * 8 + u + 1;
                q0 += ring[u].x; q1 += ring[u].y; q2 += ring[u].z; q3 += ring[u].w;
                ring[u] = srow[w * 8 + u + 8];
                const float n   = q0 * q0 + q1 * q1 + q2 * q2 + q3 * q3;
                const float inv = __builtin_amdgcn_rsqf(n);
                q0 *= inv; q1 *= inv; q2 *= inv; q3 *= inv;
                qrow[t] = make_float4(q0, q1, q2, q3);
            }
        }
#pragma unroll
        for (int u = 0; u < 7; ++u) {              // tail t = 121..127
            const int t = 121 + u;
            q0 += ring[u].x; q1 += ring[u].y; q2 += ring[u].z; q3 += ring[u].w;
            const float n   = q0 * q0 + q1 * q1 + q2 * q2 + q3 * q3;
            const float inv = __builtin_amdgcn_rsqf(n);
            q0 *= inv; q1 *= inv; q2 *= inv; q3 *= inv;
            qrow[t] = make_float4(q0, q1, q2, q3);
        }
    }
    __syncthreads();

    // ---- P3: pos + quat stores ----
    if (valid) {
        const float4 q = squat[row][s];
        o[0] = ginit[row][0] + ix - d0;   // exclusive prefix = inclusive - own
        o[1] = ginit[row][1] + iy - d1;
        o[2] = ginit[row][2] + iz - d2;
        o[3] = q.x; o[4] = q.y; o[5] = q.z; o[6] = q.w;
    }
}

extern "C" void kernel_launch(void* const* d_in, const int* in_sizes, int n_in,
                              void* d_out, int out_size, void* d_ws, size_t ws_size,
                              hipStream_t stream) {
    const float* dba = (const float*)d_in[0];   // (B, 128, 32)
    // d_in[1] = imu_measurements — unused by the reference
    const float* gt  = (const float*)d_in[2];   // (B, 128, 15)
    float* out = (float*)d_out;                 // (B, 128, 15)

    const int B = in_sizes[0] / (SEQ * REC);
    const int blocks = (B + RPB - 1) / RPB;
    fused_kernel<<<blocks, NT, 0, stream>>>(dba, gt, out, B);
}